// Round 6
// baseline (44.717 us; speedup 1.0000x reference)
//
#include <hip/hip_runtime.h>

#define D_ROWS 136
#define B_COLS 131072            // 2^17
#define NTHREADS 256
#define ROWS_PER_CHUNK 8
#define ROW_CHUNKS (D_ROWS / ROWS_PER_CHUNK)   // 17
#define CQ_TOTAL (B_COLS / 4)                  // 32768 column-quads
#define CQ_BLOCKS (CQ_TOTAL / NTHREADS)        // 128
#define C2_TOTAL (B_COLS / 2)                  // 65536 column-pairs

// ---------------------------------------------------------------------------
// Kernel 1: per-column weight (float2 path -> 1024 waves for faster ramp),
// also zeroes out[0] for the mse kernel's atomic accumulation.
// ---------------------------------------------------------------------------
__global__ __launch_bounds__(NTHREADS) void weight_kernel(
    const float2* __restrict__ ea,        // [3][B/2]
    const int2*   __restrict__ attr,      // [6][B/2]
    const float*  __restrict__ attr_num,  // [6]
    float2*       __restrict__ weight,    // [B/2]
    float*        __restrict__ out)
{
    int c2 = blockIdx.x * blockDim.x + threadIdx.x;   // 0..65535

    if (blockIdx.x == 0 && threadIdx.x == 0) out[0] = 0.f;
    if (c2 >= C2_TOTAL) return;

    float total = attr_num[0] + attr_num[1] + attr_num[2] +
                  attr_num[3] + attr_num[4] + attr_num[5];

    float aw0 = 0.f, aw1 = 0.f;
#pragma unroll
    for (int j = 0; j < 6; ++j) {
        int2 a = attr[j * C2_TOTAL + c2];
        float f = total / attr_num[j];
        aw0 += (a.x == 1) ? f : 0.f;
        aw1 += (a.y == 1) ? f : 0.f;
    }

    float an0 = 0.f, an1 = 0.f;
#pragma unroll
    for (int j = 0; j < 3; ++j) {
        float2 e = ea[j * C2_TOTAL + c2];
        an0 += 1.f - cosf(e.x);
        an1 += 1.f - cosf(e.y);
    }

    float2 w;
    w.x = aw0 * an0;
    w.y = aw1 * an1;
    weight[c2] = w;
}

// ---------------------------------------------------------------------------
// Kernel 2: weighted SSE over an 8-row x column-quad tile per thread, block
// reduce, then ONE un-fenced float atomicAdd of the pre-scaled partial into
// out[0]. No ticket, no __threadfence, no final kernel (R4's poison removed).
// ---------------------------------------------------------------------------
__global__ __launch_bounds__(NTHREADS) void mse_kernel(
    const float4* __restrict__ inp,
    const float4* __restrict__ label,
    const float4* __restrict__ weight4,
    float*        __restrict__ out)
{
    const int cq  = blockIdx.x * blockDim.x + threadIdx.x;   // 0..32767
    const int idx = blockIdx.y * ROWS_PER_CHUNK * CQ_TOTAL + cq;

    float4 w = weight4[cq];
    float4 av[ROWS_PER_CHUNK];
    float4 lv[ROWS_PER_CHUNK];
#pragma unroll
    for (int r = 0; r < ROWS_PER_CHUNK; ++r)
        av[r] = inp[idx + r * CQ_TOTAL];
#pragma unroll
    for (int r = 0; r < ROWS_PER_CHUNK; ++r)
        lv[r] = label[idx + r * CQ_TOTAL];

    float acc = 0.f;
#pragma unroll
    for (int r = 0; r < ROWS_PER_CHUNK; ++r) {
        float dx = av[r].x - lv[r].x;
        float dy = av[r].y - lv[r].y;
        float dz = av[r].z - lv[r].z;
        float dw = av[r].w - lv[r].w;
        acc += w.x * dx * dx + w.y * dy * dy + w.z * dz * dz + w.w * dw * dw;
    }

    // 64-lane wave shuffle reduce
    for (int off = 32; off > 0; off >>= 1)
        acc += __shfl_down(acc, off, 64);

    __shared__ double sw[NTHREADS / 64];
    int lane = threadIdx.x & 63;
    int wid  = threadIdx.x >> 6;
    if (lane == 0) sw[wid] = (double)acc;
    __syncthreads();

    if (threadIdx.x == 0) {
        double s = sw[0] + sw[1] + sw[2] + sw[3];
        const double invN = 1.0 / ((double)D_ROWS * (double)B_COLS);
        atomicAdd(out, (float)(s * invN));
    }
}

// ---------------------------------------------------------------------------
extern "C" void kernel_launch(void* const* d_in, const int* in_sizes, int n_in,
                              void* d_out, int out_size, void* d_ws, size_t ws_size,
                              hipStream_t stream) {
    const float* inp      = (const float*)d_in[0];   // [D][B]
    const float* label    = (const float*)d_in[1];   // [D][B]
    const float* ea       = (const float*)d_in[2];   // [3][B]
    const int*   attr     = (const int*)d_in[3];     // [6][B]
    const float* attr_num = (const float*)d_in[4];   // [6]
    float* out = (float*)d_out;

    // ws layout: weight [B] floats
    float* weight = (float*)d_ws;

    weight_kernel<<<C2_TOTAL / NTHREADS, NTHREADS, 0, stream>>>(
        (const float2*)ea, (const int2*)attr, attr_num, (float2*)weight, out);

    mse_kernel<<<dim3(CQ_BLOCKS, ROW_CHUNKS), NTHREADS, 0, stream>>>(
        (const float4*)inp, (const float4*)label, (const float4*)weight, out);
}

// Round 7
// 32.905 us; speedup vs baseline: 1.3590x; 1.3590x over previous
//
#include <hip/hip_runtime.h>

#define D_ROWS 136
#define B_COLS 131072            // 2^17
#define NTHREADS 256
#define ROWS_PER_CHUNK 8
#define ROW_CHUNKS (D_ROWS / ROWS_PER_CHUNK)   // 17
#define CQ_TOTAL (B_COLS / 4)                  // 32768 column-quads
#define CQ_BLOCKS (CQ_TOTAL / NTHREADS)        // 128
#define NPARTIALS (CQ_BLOCKS * ROW_CHUNKS)     // 2176

// ---------------------------------------------------------------------------
// Fused kernel: each thread owns one column-quad x 8 rows AND recomputes its
// quad's weight from ea/attr directly (no weight array, no weight kernel, no
// extra dispatch boundary). ea/attr are re-read by all 17 row-chunks but are
// L2/LLC-resident (4.7 MB) after first touch.
// ---------------------------------------------------------------------------
__global__ __launch_bounds__(NTHREADS) void mse_fused_kernel(
    const float4* __restrict__ inp,       // [D][B/4]
    const float4* __restrict__ label,     // [D][B/4]
    const float4* __restrict__ ea,        // [3][B/4]
    const int4*   __restrict__ attr,      // [6][B/4]
    const float*  __restrict__ attr_num,  // [6]
    double*       __restrict__ partials)
{
    const int cq  = blockIdx.x * blockDim.x + threadIdx.x;   // 0..32767
    const int idx = blockIdx.y * ROWS_PER_CHUNK * CQ_TOTAL + cq;

    // Issue the heavy data stream first.
    float4 av[ROWS_PER_CHUNK];
    float4 lv[ROWS_PER_CHUNK];
#pragma unroll
    for (int r = 0; r < ROWS_PER_CHUNK; ++r)
        av[r] = inp[idx + r * CQ_TOTAL];
#pragma unroll
    for (int r = 0; r < ROWS_PER_CHUNK; ++r)
        lv[r] = label[idx + r * CQ_TOTAL];

    // Weight inputs (L2-hot after first row-chunk touches them).
    float total = attr_num[0] + attr_num[1] + attr_num[2] +
                  attr_num[3] + attr_num[4] + attr_num[5];

    float aw0 = 0.f, aw1 = 0.f, aw2 = 0.f, aw3 = 0.f;
#pragma unroll
    for (int j = 0; j < 6; ++j) {
        int4 a = attr[j * CQ_TOTAL + cq];
        float f = total / attr_num[j];
        aw0 += (a.x == 1) ? f : 0.f;
        aw1 += (a.y == 1) ? f : 0.f;
        aw2 += (a.z == 1) ? f : 0.f;
        aw3 += (a.w == 1) ? f : 0.f;
    }

    float an0 = 0.f, an1 = 0.f, an2 = 0.f, an3 = 0.f;
#pragma unroll
    for (int j = 0; j < 3; ++j) {
        float4 e = ea[j * CQ_TOTAL + cq];
        an0 += 1.f - cosf(e.x);
        an1 += 1.f - cosf(e.y);
        an2 += 1.f - cosf(e.z);
        an3 += 1.f - cosf(e.w);
    }

    float4 w;
    w.x = aw0 * an0;
    w.y = aw1 * an1;
    w.z = aw2 * an2;
    w.w = aw3 * an3;

    float acc = 0.f;
#pragma unroll
    for (int r = 0; r < ROWS_PER_CHUNK; ++r) {
        float dx = av[r].x - lv[r].x;
        float dy = av[r].y - lv[r].y;
        float dz = av[r].z - lv[r].z;
        float dw = av[r].w - lv[r].w;
        acc += w.x * dx * dx + w.y * dy * dy + w.z * dz * dz + w.w * dw * dw;
    }

    // 64-lane wave shuffle reduce
    for (int off = 32; off > 0; off >>= 1)
        acc += __shfl_down(acc, off, 64);

    __shared__ double sw[NTHREADS / 64];
    int lane = threadIdx.x & 63;
    int wid  = threadIdx.x >> 6;
    if (lane == 0) sw[wid] = (double)acc;
    __syncthreads();
    if (threadIdx.x == 0) {
        double s = sw[0] + sw[1] + sw[2] + sw[3];
        partials[blockIdx.y * gridDim.x + blockIdx.x] = s;
    }
}

// ---------------------------------------------------------------------------
// Final reduce of block partials -> mean
// ---------------------------------------------------------------------------
__global__ __launch_bounds__(NTHREADS) void final_kernel(
    const double* __restrict__ partials,
    int n,
    float* __restrict__ out)
{
    double acc = 0.0;
    for (int i = threadIdx.x; i < n; i += blockDim.x) acc += partials[i];

    for (int off = 32; off > 0; off >>= 1)
        acc += __shfl_down(acc, off, 64);

    __shared__ double sw[NTHREADS / 64];
    int lane = threadIdx.x & 63;
    int wid  = threadIdx.x >> 6;
    if (lane == 0) sw[wid] = acc;
    __syncthreads();
    if (threadIdx.x == 0) {
        double s = 0.0;
#pragma unroll
        for (int v = 0; v < NTHREADS / 64; ++v) s += sw[v];
        out[0] = (float)(s / ((double)D_ROWS * (double)B_COLS));
    }
}

// ---------------------------------------------------------------------------
extern "C" void kernel_launch(void* const* d_in, const int* in_sizes, int n_in,
                              void* d_out, int out_size, void* d_ws, size_t ws_size,
                              hipStream_t stream) {
    const float* inp      = (const float*)d_in[0];   // [D][B]
    const float* label    = (const float*)d_in[1];   // [D][B]
    const float* ea       = (const float*)d_in[2];   // [3][B]
    const int*   attr     = (const int*)d_in[3];     // [6][B]
    const float* attr_num = (const float*)d_in[4];   // [6]
    float* out = (float*)d_out;

    double* partials = (double*)d_ws;

    mse_fused_kernel<<<dim3(CQ_BLOCKS, ROW_CHUNKS), NTHREADS, 0, stream>>>(
        (const float4*)inp, (const float4*)label, (const float4*)ea,
        (const int4*)attr, attr_num, partials);

    final_kernel<<<1, NTHREADS, 0, stream>>>(partials, NPARTIALS, out);
}